// Round 4
// baseline (1175.400 us; speedup 1.0000x reference)
//
#include <hip/hip_runtime.h>
#include <hip/hip_bf16.h>

#define B_ 8
#define T_ 8192
#define M_ (B_ * T_)          // 65536 rows
#define IDIM 256
#define HDIM 1024
#define ODIM 256
#define CDIM 128
#define OUT_OFF ((size_t)M_ * ODIM)   // start of mask_new region in d_out

typedef __attribute__((ext_vector_type(4))) float floatx4;
typedef __attribute__((ext_vector_type(8))) short shortx8;

// async global->LDS, 16B per lane (dest = wave-uniform base + lane*16)
__device__ __forceinline__ void glds16(const float* g, void* lds) {
    __builtin_amdgcn_global_load_lds(
        (const __attribute__((address_space(1))) void*)g,
        (__attribute__((address_space(3))) void*)lds, 16, 0, 0);
}

// ---------------------------------------------------------------------------
// K0: WdT[n][k] = bf16(W_dec_sel[k][n])
// ---------------------------------------------------------------------------
__global__ __launch_bounds__(256) void k0_convw(const float* __restrict__ Wself,
                                                const float* __restrict__ Wsrc,
                                                const int* __restrict__ dtype,
                                                __hip_bfloat16* __restrict__ WdT) {
    int id = blockIdx.x * 256 + threadIdx.x;
    int n = id >> 10;
    int k = id & 1023;
    const float* W = (*dtype == 0) ? Wself : Wsrc;
    WdT[id] = __float2bfloat16(W[(size_t)k * ODIM + n]);
}

// ---------------------------------------------------------------------------
// K1: encoder GEMM fp32 — BIT-EXACT fma chain (k ascending per acc element).
// h feeds a top-k vs np's reference: any change to fma order/precision risks
// boundary flips (round-1: bf16x6 MFMA failed absmax 0.044 > 0.0327).
// STATUS after rounds 0/2/3: 407 µs / VALUBusy 75% invariant across three
// schedules (conflicts 0, pipeline, occupancy 32-41%) => VALU-issue
// saturated at ~84 TF (82% of m07's 103 TF measured fma floor). Near ceiling.
// Round-4 trim: eliminate av[]/bv[] temp arrays (direct float4-component
// fma) in case SROA materialized them as v_mov — bit-exact, zero risk.
// ---------------------------------------------------------------------------
__global__ __launch_bounds__(256, 3) void k1_enc(const float* __restrict__ X,
                                                 const float* __restrict__ W,
                                                 const float* __restrict__ bias,
                                                 float* __restrict__ H) {
    __shared__ __align__(16) float As[32][128];      // [k][m ^ (k&28)]
    __shared__ __align__(16) float Bs[2][32][128];   // [buf][k][n]
    const int t  = threadIdx.x;
    const int m0 = blockIdx.x * 128;
    const int n0 = blockIdx.y * 128;
    const int tx = t & 15;
    const int ty = t >> 4;
    const int wavebase = t & ~63;   // wave*64

    int acol[4], ak4[4];
    const float* aptr[4];
#pragma unroll
    for (int r = 0; r < 4; ++r) {
        int idx = r * 256 + t;
        int row = idx >> 3;
        int k4  = (idx & 7) << 2;
        ak4[r]  = k4;
        acol[r] = row ^ k4;
        aptr[r] = X + (size_t)(m0 + row) * IDIM + k4;
    }
    const float* bptr[4];
#pragma unroll
    for (int r = 0; r < 4; ++r) {
        int idx = r * 256 + t;
        int row = idx >> 5;
        int c4  = (idx & 31) << 2;
        bptr[r] = W + (size_t)row * HDIM + n0 + c4;
    }

    float acc[8][8];
#pragma unroll
    for (int i = 0; i < 8; ++i)
#pragma unroll
        for (int j = 0; j < 8; ++j) acc[i][j] = 0.0f;

    float4 areg[4];

    // ---- prologue: stage tile 0 ----
#pragma unroll
    for (int r = 0; r < 4; ++r) areg[r] = *(const float4*)(aptr[r]);
#pragma unroll
    for (int r = 0; r < 4; ++r)
        glds16(bptr[r], (char*)&Bs[0][0][0] + (size_t)(r * 256 + wavebase) * 16);
#pragma unroll
    for (int r = 0; r < 4; ++r) {
        As[ak4[r] + 0][acol[r]] = areg[r].x;
        As[ak4[r] + 1][acol[r]] = areg[r].y;
        As[ak4[r] + 2][acol[r]] = areg[r].z;
        As[ak4[r] + 3][acol[r]] = areg[r].w;
    }
    asm volatile("s_waitcnt vmcnt(0)");
    __syncthreads();

#pragma unroll 1
    for (int tt = 0; tt < IDIM / 32; ++tt) {
        const int cur = tt & 1;
        if (tt < IDIM / 32 - 1) {
            const int kn = (tt + 1) * 32;
#pragma unroll
            for (int r = 0; r < 4; ++r)
                glds16(bptr[r] + (size_t)kn * HDIM,
                       (char*)&Bs[cur ^ 1][0][0] + (size_t)(r * 256 + wavebase) * 16);
#pragma unroll
            for (int r = 0; r < 4; ++r) areg[r] = *(const float4*)(aptr[r] + kn);
        }

#pragma unroll 8
        for (int k = 0; k < 32; ++k) {
            const int s = k & 28;
            float4 a0 = *(const float4*)&As[k][(ty * 8) ^ s];
            float4 a1 = *(const float4*)&As[k][(ty * 8 + 4) ^ s];
            float4 b0 = *(const float4*)&Bs[cur][k][tx * 4];
            float4 b1 = *(const float4*)&Bs[cur][k][tx * 4 + 64];
#define FMA_ROW(i, ax)                              \
            acc[i][0] = fmaf(ax, b0.x, acc[i][0]);  \
            acc[i][1] = fmaf(ax, b0.y, acc[i][1]);  \
            acc[i][2] = fmaf(ax, b0.z, acc[i][2]);  \
            acc[i][3] = fmaf(ax, b0.w, acc[i][3]);  \
            acc[i][4] = fmaf(ax, b1.x, acc[i][4]);  \
            acc[i][5] = fmaf(ax, b1.y, acc[i][5]);  \
            acc[i][6] = fmaf(ax, b1.z, acc[i][6]);  \
            acc[i][7] = fmaf(ax, b1.w, acc[i][7]);
            FMA_ROW(0, a0.x) FMA_ROW(1, a0.y) FMA_ROW(2, a0.z) FMA_ROW(3, a0.w)
            FMA_ROW(4, a1.x) FMA_ROW(5, a1.y) FMA_ROW(6, a1.z) FMA_ROW(7, a1.w)
#undef FMA_ROW
        }

        if (tt < IDIM / 32 - 1) {
            asm volatile("s_waitcnt vmcnt(0)");
            __syncthreads();
#pragma unroll
            for (int r = 0; r < 4; ++r) {
                As[ak4[r] + 0][acol[r]] = areg[r].x;
                As[ak4[r] + 1][acol[r]] = areg[r].y;
                As[ak4[r] + 2][acol[r]] = areg[r].z;
                As[ak4[r] + 3][acol[r]] = areg[r].w;
            }
            __syncthreads();
        }
    }

#pragma unroll
    for (int i = 0; i < 8; ++i) {
        int gm = m0 + ty * 8 + i;
        float* o = H + (size_t)gm * HDIM + n0;
        float4 v0, v1;
        v0.x = acc[i][0] + bias[n0 + tx * 4 + 0];
        v0.y = acc[i][1] + bias[n0 + tx * 4 + 1];
        v0.z = acc[i][2] + bias[n0 + tx * 4 + 2];
        v0.w = acc[i][3] + bias[n0 + tx * 4 + 3];
        v1.x = acc[i][4] + bias[n0 + 64 + tx * 4 + 0];
        v1.y = acc[i][5] + bias[n0 + 64 + tx * 4 + 1];
        v1.z = acc[i][6] + bias[n0 + 64 + tx * 4 + 2];
        v1.w = acc[i][7] + bias[n0 + 64 + tx * 4 + 3];
        *(float4*)(o + tx * 4) = v0;
        *(float4*)(o + 64 + tx * 4) = v1;
    }
}

// ---------------------------------------------------------------------------
// K2: per-row top-128/top-256 by energy.
// Round-4: single-wave blocks (64 threads, grid=M_). Round-3 counters showed
// 207 µs with VALU 43% / HBM 40% / occ 42% — latency-bound, not pipe-bound.
// All shared state was already per-wave; the 6 __syncthreads per row coupled
// 4 independent rows' dependency chains. One wave per block decouples them
// (barriers degenerate to intra-wave waits) and raises independent rows/CU.
// Selection logic is UNCHANGED (harness-verified).
// ---------------------------------------------------------------------------
#define NBIN 512
#define KBASE 1600
#define CAP 128

__device__ __forceinline__ unsigned int bsearch_kth(const unsigned int* u, int k,
                                                    int lane, int* r_out) {
    unsigned long long lo = 0, hi = 0xFFFFFFFFull;
    while (lo < hi) {
        unsigned int mid = (unsigned int)((lo + hi + 1) >> 1);
        int c = 0;
#pragma unroll
        for (int i = 0; i < 16; ++i) c += (u[i] >= mid) ? 1 : 0;
#pragma unroll
        for (int off = 1; off < 64; off <<= 1) {
            int o = __shfl_down(c, off, 64);
            if (lane + off < 64) c += o;
        }
        c = __shfl(c, 0);
        if (c >= k) lo = mid; else hi = (unsigned long long)mid - 1;
    }
    unsigned int T = (unsigned int)lo;
    int g = 0;
#pragma unroll
    for (int i = 0; i < 16; ++i) g += (u[i] > T) ? 1 : 0;
#pragma unroll
    for (int off = 1; off < 64; off <<= 1) {
        int o = __shfl_down(g, off, 64);
        if (lane + off < 64) g += o;
    }
    g = __shfl(g, 0);
    *r_out = k - g;
    return T;
}

__global__ __launch_bounds__(64) void k2_topk(const float* __restrict__ mask_prev,
                                              float* __restrict__ Hio,
                                              __hip_bfloat16* __restrict__ Abf) {
    __shared__ unsigned int hist[NBIN];
    __shared__ unsigned long long cand[2][CAP];
    __shared__ unsigned int sres[8];   // b1,kk1,b2,kk2, T1,g1, T2,g2
    __shared__ unsigned int scnt[2];
    const int lane = threadIdx.x;
    const size_t row = (size_t)blockIdx.x;
    const float* mp = mask_prev + row * HDIM + lane * 16;
    float* hrow = Hio + row * HDIM + lane * 16;

    float hv[16], mpv[16];
    unsigned int u[16];
    int bin[16];
#pragma unroll
    for (int c = 0; c < 4; ++c) {
        float4 m4 = *(const float4*)(mp + c * 4);
        float4 h4 = *(const float4*)(hrow + c * 4);
        float mm[4] = {m4.x, m4.y, m4.z, m4.w};
        float hh[4] = {h4.x, h4.y, h4.z, h4.w};
#pragma unroll
        for (int x = 0; x < 4; ++x) {
            int i = c * 4 + x;
            float h = (mm[x] > 0.0f) ? 0.0f : hh[x];
            mpv[i] = mm[x]; hv[i] = h;
            u[i] = __float_as_uint(h * h);
            int b = (int)(u[i] >> 19) - KBASE;
            bin[i] = (b < 0) ? 0 : ((b > NBIN - 1) ? NBIN - 1 : b);
        }
    }

    // zero + histogram
#pragma unroll
    for (int q = 0; q < 8; ++q) hist[lane + (q << 6)] = 0u;
    if (lane < 2) scnt[lane] = 0u;
    __syncthreads();
#pragma unroll
    for (int i = 0; i < 16; ++i) atomicAdd(&hist[bin[i]], 1u);
    __syncthreads();

    // combined scan for k=128 and k=256 (descending bins)
    {
        unsigned int cj[8]; unsigned int lt = 0;
#pragma unroll
        for (int jj = 0; jj < 8; ++jj) { cj[jj] = hist[lane * 8 + jj]; lt += cj[jj]; }
        unsigned int s = lt;
#pragma unroll
        for (int off = 1; off < 64; off <<= 1) {
            unsigned int o = (unsigned int)__shfl_down((int)s, off, 64);
            if (lane + off < 64) s += o;
        }
        unsigned int run = s - lt;    // count in bins above my top bin
#pragma unroll
        for (int jj = 7; jj >= 0; --jj) {
            unsigned int gt = run, ge = run + cj[jj];
            if (gt < CDIM && CDIM <= ge)         { sres[0] = lane * 8 + jj; sres[1] = CDIM - gt; }
            if (gt < 2 * CDIM && 2 * CDIM <= ge) { sres[2] = lane * 8 + jj; sres[3] = 2 * CDIM - gt; }
            run = ge;
        }
    }
    __syncthreads();
    const unsigned int b1 = sres[0], kk1 = sres[1];
    const unsigned int b2 = sres[2], kk2 = sres[3];

    // gather boundary-bin candidates (j = lane*16 + i)
#pragma unroll
    for (int i = 0; i < 16; ++i) {
        int j = lane * 16 + i;
        unsigned long long pk = ((unsigned long long)u[i] << 32) | (unsigned int)(1023 - j);
        if ((unsigned int)bin[i] == b1) {
            unsigned int p = atomicAdd(&scnt[0], 1u);
            if (p < CAP) cand[0][p] = pk;
        }
        if (b2 != b1 && (unsigned int)bin[i] == b2) {
            unsigned int p = atomicAdd(&scnt[1], 1u);
            if (p < CAP) cand[1][p] = pk;
        }
    }
    __syncthreads();
    const unsigned int C1 = scnt[0];
    const unsigned int C2 = (b2 == b1) ? C1 : scnt[1];
    const unsigned long long* L2 = (b2 == b1) ? cand[0] : cand[1];

    // exact rank within boundary bin
    if (C1 <= CAP) {
        for (unsigned int idx = lane; idx < C1; idx += 64) {
            unsigned long long mine = cand[0][idx];
            unsigned int myu = (unsigned int)(mine >> 32);
            unsigned int rank = 0, gtu = 0;
            for (unsigned int c = 0; c < C1; ++c) {
                unsigned long long o = cand[0][c];
                rank += (o > mine) ? 1u : 0u;
                gtu  += ((unsigned int)(o >> 32) > myu) ? 1u : 0u;
            }
            if (rank == kk1 - 1) { sres[4] = myu; sres[5] = gtu; }
        }
    }
    if (C2 <= CAP) {
        for (unsigned int idx = lane; idx < C2; idx += 64) {
            unsigned long long mine = L2[idx];
            unsigned int myu = (unsigned int)(mine >> 32);
            unsigned int rank = 0, gtu = 0;
            for (unsigned int c = 0; c < C2; ++c) {
                unsigned long long o = L2[c];
                rank += (o > mine) ? 1u : 0u;
                gtu  += ((unsigned int)(o >> 32) > myu) ? 1u : 0u;
            }
            if (rank == kk2 - 1) { sres[6] = myu; sres[7] = gtu; }
        }
    }
    __syncthreads();

    unsigned int T1, T2; int r1, r2;
    if (C1 <= CAP) { T1 = sres[4]; r1 = (int)(kk1 - sres[5]); }
    else           { T1 = bsearch_kth(u, CDIM, lane, &r1); }
    if (C2 <= CAP) { T2 = sres[6]; r2 = (int)(kk2 - sres[7]); }
    else           { T2 = bsearch_kth(u, 2 * CDIM, lane, &r2); }

    // tie ranks for (lane, i) ascending-index order
    int p1[16], p2[16];
    int tot1 = 0, tot2 = 0;
#pragma unroll
    for (int i = 0; i < 16; ++i) {
        p1[i] = tot1; p2[i] = tot2;
        tot1 += (u[i] == T1) ? 1 : 0;
        tot2 += (u[i] == T2) ? 1 : 0;
    }
    int s1v = tot1, s2v = tot2;
#pragma unroll
    for (int off = 1; off < 64; off <<= 1) {
        int o1 = __shfl_up(s1v, off, 64);
        int o2 = __shfl_up(s2v, off, 64);
        if (lane >= off) { s1v += o1; s2v += o2; }
    }
    const int ex1 = s1v - tot1;
    const int ex2 = s2v - tot2;

    // mask_new store: 4x float4
#pragma unroll
    for (int c = 0; c < 4; ++c) {
        float v[4];
#pragma unroll
        for (int x = 0; x < 4; ++x) {
            int i = c * 4 + x;
            bool s1 = (u[i] > T1) || ((u[i] == T1) && (ex1 + p1[i] < r1));
            v[x] = mpv[i] + (s1 ? 1.0f : 0.0f);
        }
        float4 v4 = {v[0], v[1], v[2], v[3]};
        *(float4*)(hrow + c * 4) = v4;
    }
    // Abf store: 2x uint4 (8 bf16 each)
    __hip_bfloat16* ab = Abf + row * HDIM + lane * 16;
#pragma unroll
    for (int half = 0; half < 2; ++half) {
        union { unsigned short us[8]; uint4 v; } pk;
#pragma unroll
        for (int x = 0; x < 8; ++x) {
            int i = half * 8 + x;
            bool s2 = (u[i] > T2) || ((u[i] == T2) && (ex2 + p2[i] < r2));
            __hip_bfloat16 bb = __float2bfloat16(s2 ? hv[i] : 0.0f);
            pk.us[x] = *(unsigned short*)&bb;
        }
        *(uint4*)(ab + half * 8) = pk.v;
    }
}

// ---------------------------------------------------------------------------
// K3: decoder GEMM bf16 MFMA, 128x128 tile, BK=32, padded LDS (K3LD=40),
// register prefetch (unchanged — harness-verified).
// ---------------------------------------------------------------------------
#define K3LD 40
__global__ __launch_bounds__(256) void k3_dec(const __hip_bfloat16* __restrict__ A,
                                              const __hip_bfloat16* __restrict__ Bt,
                                              const float* __restrict__ bias_self,
                                              const float* __restrict__ bias_src,
                                              const int* __restrict__ dtype,
                                              float* __restrict__ Out) {
    __shared__ __align__(16) __hip_bfloat16 As[128 * K3LD];
    __shared__ __align__(16) __hip_bfloat16 Bs[128 * K3LD];
    const int t = threadIdx.x;
    const int lane = t & 63;
    const int wave = t >> 6;
    const int m0 = blockIdx.x * 128;
    const int n0 = blockIdx.y * 128;
    const int wr = wave >> 1;
    const int wc = wave & 1;
    const int quad = lane >> 4;
    const int rf = lane & 15;

    int srow[2], skc[2];
#pragma unroll
    for (int p = 0; p < 2; ++p) {
        int l = p * 256 + t;
        srow[p] = l >> 2;
        skc[p]  = (l & 3) << 3;
    }

    floatx4 acc[4][4];
    const floatx4 z = {0.0f, 0.0f, 0.0f, 0.0f};
#pragma unroll
    for (int i = 0; i < 4; ++i)
#pragma unroll
        for (int j = 0; j < 4; ++j) acc[i][j] = z;

    uint4 apre[2], bpre[2];
#pragma unroll
    for (int p = 0; p < 2; ++p) {
        apre[p] = *(const uint4*)(A  + (size_t)(m0 + srow[p]) * HDIM + skc[p]);
        bpre[p] = *(const uint4*)(Bt + (size_t)(n0 + srow[p]) * HDIM + skc[p]);
    }
#pragma unroll
    for (int p = 0; p < 2; ++p) {
        *(uint4*)&As[srow[p] * K3LD + skc[p]] = apre[p];
        *(uint4*)&Bs[srow[p] * K3LD + skc[p]] = bpre[p];
    }
    __syncthreads();

#pragma unroll 1
    for (int kt = 0; kt < HDIM / 32; ++kt) {
        if (kt < HDIM / 32 - 1) {
            int kn = (kt + 1) * 32;
#pragma unroll
            for (int p = 0; p < 2; ++p) {
                apre[p] = *(const uint4*)(A  + (size_t)(m0 + srow[p]) * HDIM + kn + skc[p]);
                bpre[p] = *(const uint4*)(Bt + (size_t)(n0 + srow[p]) * HDIM + kn + skc[p]);
            }
        }
        shortx8 af[4], bf[4];
#pragma unroll
        for (int i = 0; i < 4; ++i) {
            af[i] = *(const shortx8*)&As[(wr * 64 + i * 16 + rf) * K3LD + quad * 8];
            bf[i] = *(const shortx8*)&Bs[(wc * 64 + i * 16 + rf) * K3LD + quad * 8];
        }
#pragma unroll
        for (int mi = 0; mi < 4; ++mi)
#pragma unroll
            for (int nj = 0; nj < 4; ++nj)
                acc[mi][nj] = __builtin_amdgcn_mfma_f32_16x16x32_bf16(
                    af[mi], bf[nj], acc[mi][nj], 0, 0, 0);
        __syncthreads();
        if (kt < HDIM / 32 - 1) {
#pragma unroll
            for (int p = 0; p < 2; ++p) {
                *(uint4*)&As[srow[p] * K3LD + skc[p]] = apre[p];
                *(uint4*)&Bs[srow[p] * K3LD + skc[p]] = bpre[p];
            }
            __syncthreads();
        }
    }

    const float* bias = (*dtype == 0) ? bias_self : bias_src;
#pragma unroll
    for (int mi = 0; mi < 4; ++mi) {
#pragma unroll
        for (int nj = 0; nj < 4; ++nj) {
            int gn = n0 + wc * 64 + nj * 16 + rf;
            float bv = bias[gn];
            int gmb = m0 + wr * 64 + mi * 16 + quad * 4;
#pragma unroll
            for (int r2 = 0; r2 < 4; ++r2)
                Out[(size_t)(gmb + r2) * ODIM + gn] = acc[mi][nj][r2] + bv;
        }
    }
}

// ---------------------------------------------------------------------------
extern "C" void kernel_launch(void* const* d_in, const int* in_sizes, int n_in,
                              void* d_out, int out_size, void* d_ws, size_t ws_size,
                              hipStream_t stream) {
    const float* x          = (const float*)d_in[0];
    const float* mask_prev  = (const float*)d_in[1];
    const float* W_enc      = (const float*)d_in[2];
    const float* b_enc      = (const float*)d_in[3];
    const float* W_dec_self = (const float*)d_in[4];
    const float* b_dec_self = (const float*)d_in[5];
    const float* W_dec_src  = (const float*)d_in[6];
    const float* b_dec_src  = (const float*)d_in[7];
    const int*   dtype      = (const int*)d_in[8];

    float* out  = (float*)d_out;
    float* Hbuf = out + OUT_OFF;   // h staged in mask_new output region (in-place per row)

    __hip_bfloat16* Abf = (__hip_bfloat16*)d_ws;                             // 128 MB
    __hip_bfloat16* WdT = (__hip_bfloat16*)((char*)d_ws + (size_t)M_ * HDIM * 2);

    k0_convw<<<dim3((ODIM * HDIM) / 256), 256, 0, stream>>>(W_dec_self, W_dec_src, dtype, WdT);
    k1_enc  <<<dim3(M_ / 128, HDIM / 128), 256, 0, stream>>>(x, W_enc, b_enc, Hbuf);
    k2_topk <<<dim3(M_), 64, 0, stream>>>(mask_prev, Hbuf, Abf);
    k3_dec  <<<dim3(M_ / 128, ODIM / 128), 256, 0, stream>>>(Abf, WdT, b_dec_self, b_dec_src, dtype, out);
}

// Round 5
// 1054.686 us; speedup vs baseline: 1.1145x; 1.1145x over previous
//
#include <hip/hip_runtime.h>
#include <hip/hip_bf16.h>

#define B_ 8
#define T_ 8192
#define M_ (B_ * T_)          // 65536 rows
#define IDIM 256
#define HDIM 1024
#define ODIM 256
#define CDIM 128
#define OUT_OFF ((size_t)M_ * ODIM)   // start of mask_new region in d_out

typedef __attribute__((ext_vector_type(4))) float floatx4;
typedef __attribute__((ext_vector_type(8))) short shortx8;

// async global->LDS, 16B per lane (dest = wave-uniform base + lane*16)
__device__ __forceinline__ void glds16(const void* g, void* lds) {
    __builtin_amdgcn_global_load_lds(
        (const __attribute__((address_space(1))) void*)g,
        (__attribute__((address_space(3))) void*)lds, 16, 0, 0);
}

// ---------------------------------------------------------------------------
// K0: WdT[n][k] = bf16(W_dec_sel[k][n])
// ---------------------------------------------------------------------------
__global__ __launch_bounds__(256) void k0_convw(const float* __restrict__ Wself,
                                                const float* __restrict__ Wsrc,
                                                const int* __restrict__ dtype,
                                                __hip_bfloat16* __restrict__ WdT) {
    int id = blockIdx.x * 256 + threadIdx.x;
    int n = id >> 10;
    int k = id & 1023;
    const float* W = (*dtype == 0) ? Wself : Wsrc;
    WdT[id] = __float2bfloat16(W[(size_t)k * ODIM + n]);
}

// ---------------------------------------------------------------------------
// K1: encoder GEMM fp32 — BIT-EXACT fma chain (k ascending per acc element).
// h feeds a top-k vs np's reference: any change to fma order/precision risks
// boundary flips (round-1: bf16x6 MFMA failed absmax 0.044 > 0.0327).
// STATUS (rounds 0/2/3/4): 407-412 µs / VALUBusy ~75% invariant across FOUR
// schedules. Diagnosis: co-saturation — 64B LDS reads per 64 fma = 1.0 B/fma,
// which at full VALU issue demands exactly the 128 B/cy/CU LDS peak. Closed
// barring a micro-tile restructure (VGPR-risky, <=15% upside). FROZEN.
// ---------------------------------------------------------------------------
__global__ __launch_bounds__(256, 3) void k1_enc(const float* __restrict__ X,
                                                 const float* __restrict__ W,
                                                 const float* __restrict__ bias,
                                                 float* __restrict__ H) {
    __shared__ __align__(16) float As[32][128];      // [k][m ^ (k&28)]
    __shared__ __align__(16) float Bs[2][32][128];   // [buf][k][n]
    const int t  = threadIdx.x;
    const int m0 = blockIdx.x * 128;
    const int n0 = blockIdx.y * 128;
    const int tx = t & 15;
    const int ty = t >> 4;
    const int wavebase = t & ~63;   // wave*64

    int acol[4], ak4[4];
    const float* aptr[4];
#pragma unroll
    for (int r = 0; r < 4; ++r) {
        int idx = r * 256 + t;
        int row = idx >> 3;
        int k4  = (idx & 7) << 2;
        ak4[r]  = k4;
        acol[r] = row ^ k4;
        aptr[r] = X + (size_t)(m0 + row) * IDIM + k4;
    }
    const float* bptr[4];
#pragma unroll
    for (int r = 0; r < 4; ++r) {
        int idx = r * 256 + t;
        int row = idx >> 5;
        int c4  = (idx & 31) << 2;
        bptr[r] = W + (size_t)row * HDIM + n0 + c4;
    }

    float acc[8][8];
#pragma unroll
    for (int i = 0; i < 8; ++i)
#pragma unroll
        for (int j = 0; j < 8; ++j) acc[i][j] = 0.0f;

    float4 areg[4];

    // ---- prologue: stage tile 0 ----
#pragma unroll
    for (int r = 0; r < 4; ++r) areg[r] = *(const float4*)(aptr[r]);
#pragma unroll
    for (int r = 0; r < 4; ++r)
        glds16(bptr[r], (char*)&Bs[0][0][0] + (size_t)(r * 256 + wavebase) * 16);
#pragma unroll
    for (int r = 0; r < 4; ++r) {
        As[ak4[r] + 0][acol[r]] = areg[r].x;
        As[ak4[r] + 1][acol[r]] = areg[r].y;
        As[ak4[r] + 2][acol[r]] = areg[r].z;
        As[ak4[r] + 3][acol[r]] = areg[r].w;
    }
    asm volatile("s_waitcnt vmcnt(0)");
    __syncthreads();

#pragma unroll 1
    for (int tt = 0; tt < IDIM / 32; ++tt) {
        const int cur = tt & 1;
        if (tt < IDIM / 32 - 1) {
            const int kn = (tt + 1) * 32;
#pragma unroll
            for (int r = 0; r < 4; ++r)
                glds16(bptr[r] + (size_t)kn * HDIM,
                       (char*)&Bs[cur ^ 1][0][0] + (size_t)(r * 256 + wavebase) * 16);
#pragma unroll
            for (int r = 0; r < 4; ++r) areg[r] = *(const float4*)(aptr[r] + kn);
        }

#pragma unroll 8
        for (int k = 0; k < 32; ++k) {
            const int s = k & 28;
            float4 a0 = *(const float4*)&As[k][(ty * 8) ^ s];
            float4 a1 = *(const float4*)&As[k][(ty * 8 + 4) ^ s];
            float4 b0 = *(const float4*)&Bs[cur][k][tx * 4];
            float4 b1 = *(const float4*)&Bs[cur][k][tx * 4 + 64];
#define FMA_ROW(i, ax)                              \
            acc[i][0] = fmaf(ax, b0.x, acc[i][0]);  \
            acc[i][1] = fmaf(ax, b0.y, acc[i][1]);  \
            acc[i][2] = fmaf(ax, b0.z, acc[i][2]);  \
            acc[i][3] = fmaf(ax, b0.w, acc[i][3]);  \
            acc[i][4] = fmaf(ax, b1.x, acc[i][4]);  \
            acc[i][5] = fmaf(ax, b1.y, acc[i][5]);  \
            acc[i][6] = fmaf(ax, b1.z, acc[i][6]);  \
            acc[i][7] = fmaf(ax, b1.w, acc[i][7]);
            FMA_ROW(0, a0.x) FMA_ROW(1, a0.y) FMA_ROW(2, a0.z) FMA_ROW(3, a0.w)
            FMA_ROW(4, a1.x) FMA_ROW(5, a1.y) FMA_ROW(6, a1.z) FMA_ROW(7, a1.w)
#undef FMA_ROW
        }

        if (tt < IDIM / 32 - 1) {
            asm volatile("s_waitcnt vmcnt(0)");
            __syncthreads();
#pragma unroll
            for (int r = 0; r < 4; ++r) {
                As[ak4[r] + 0][acol[r]] = areg[r].x;
                As[ak4[r] + 1][acol[r]] = areg[r].y;
                As[ak4[r] + 2][acol[r]] = areg[r].z;
                As[ak4[r] + 3][acol[r]] = areg[r].w;
            }
            __syncthreads();
        }
    }

#pragma unroll
    for (int i = 0; i < 8; ++i) {
        int gm = m0 + ty * 8 + i;
        float* o = H + (size_t)gm * HDIM + n0;
        float4 v0, v1;
        v0.x = acc[i][0] + bias[n0 + tx * 4 + 0];
        v0.y = acc[i][1] + bias[n0 + tx * 4 + 1];
        v0.z = acc[i][2] + bias[n0 + tx * 4 + 2];
        v0.w = acc[i][3] + bias[n0 + tx * 4 + 3];
        v1.x = acc[i][4] + bias[n0 + 64 + tx * 4 + 0];
        v1.y = acc[i][5] + bias[n0 + 64 + tx * 4 + 1];
        v1.z = acc[i][6] + bias[n0 + 64 + tx * 4 + 2];
        v1.w = acc[i][7] + bias[n0 + 64 + tx * 4 + 3];
        *(float4*)(o + tx * 4) = v0;
        *(float4*)(o + 64 + tx * 4) = v1;
    }
}

// ---------------------------------------------------------------------------
// K2: per-row top-128/top-256 by energy. Single-wave blocks (round-4 form,
// ~neutral vs 4-wave; kept). Selection logic harness-verified. FROZEN.
// ---------------------------------------------------------------------------
#define NBIN 512
#define KBASE 1600
#define CAP 128

__device__ __forceinline__ unsigned int bsearch_kth(const unsigned int* u, int k,
                                                    int lane, int* r_out) {
    unsigned long long lo = 0, hi = 0xFFFFFFFFull;
    while (lo < hi) {
        unsigned int mid = (unsigned int)((lo + hi + 1) >> 1);
        int c = 0;
#pragma unroll
        for (int i = 0; i < 16; ++i) c += (u[i] >= mid) ? 1 : 0;
#pragma unroll
        for (int off = 1; off < 64; off <<= 1) {
            int o = __shfl_down(c, off, 64);
            if (lane + off < 64) c += o;
        }
        c = __shfl(c, 0);
        if (c >= k) lo = mid; else hi = (unsigned long long)mid - 1;
    }
    unsigned int T = (unsigned int)lo;
    int g = 0;
#pragma unroll
    for (int i = 0; i < 16; ++i) g += (u[i] > T) ? 1 : 0;
#pragma unroll
    for (int off = 1; off < 64; off <<= 1) {
        int o = __shfl_down(g, off, 64);
        if (lane + off < 64) g += o;
    }
    g = __shfl(g, 0);
    *r_out = k - g;
    return T;
}

__global__ __launch_bounds__(64) void k2_topk(const float* __restrict__ mask_prev,
                                              float* __restrict__ Hio,
                                              __hip_bfloat16* __restrict__ Abf) {
    __shared__ unsigned int hist[NBIN];
    __shared__ unsigned long long cand[2][CAP];
    __shared__ unsigned int sres[8];   // b1,kk1,b2,kk2, T1,g1, T2,g2
    __shared__ unsigned int scnt[2];
    const int lane = threadIdx.x;
    const size_t row = (size_t)blockIdx.x;
    const float* mp = mask_prev + row * HDIM + lane * 16;
    float* hrow = Hio + row * HDIM + lane * 16;

    float hv[16], mpv[16];
    unsigned int u[16];
    int bin[16];
#pragma unroll
    for (int c = 0; c < 4; ++c) {
        float4 m4 = *(const float4*)(mp + c * 4);
        float4 h4 = *(const float4*)(hrow + c * 4);
        float mm[4] = {m4.x, m4.y, m4.z, m4.w};
        float hh[4] = {h4.x, h4.y, h4.z, h4.w};
#pragma unroll
        for (int x = 0; x < 4; ++x) {
            int i = c * 4 + x;
            float h = (mm[x] > 0.0f) ? 0.0f : hh[x];
            mpv[i] = mm[x]; hv[i] = h;
            u[i] = __float_as_uint(h * h);
            int b = (int)(u[i] >> 19) - KBASE;
            bin[i] = (b < 0) ? 0 : ((b > NBIN - 1) ? NBIN - 1 : b);
        }
    }

    // zero + histogram
#pragma unroll
    for (int q = 0; q < 8; ++q) hist[lane + (q << 6)] = 0u;
    if (lane < 2) scnt[lane] = 0u;
    __syncthreads();
#pragma unroll
    for (int i = 0; i < 16; ++i) atomicAdd(&hist[bin[i]], 1u);
    __syncthreads();

    // combined scan for k=128 and k=256 (descending bins)
    {
        unsigned int cj[8]; unsigned int lt = 0;
#pragma unroll
        for (int jj = 0; jj < 8; ++jj) { cj[jj] = hist[lane * 8 + jj]; lt += cj[jj]; }
        unsigned int s = lt;
#pragma unroll
        for (int off = 1; off < 64; off <<= 1) {
            unsigned int o = (unsigned int)__shfl_down((int)s, off, 64);
            if (lane + off < 64) s += o;
        }
        unsigned int run = s - lt;    // count in bins above my top bin
#pragma unroll
        for (int jj = 7; jj >= 0; --jj) {
            unsigned int gt = run, ge = run + cj[jj];
            if (gt < CDIM && CDIM <= ge)         { sres[0] = lane * 8 + jj; sres[1] = CDIM - gt; }
            if (gt < 2 * CDIM && 2 * CDIM <= ge) { sres[2] = lane * 8 + jj; sres[3] = 2 * CDIM - gt; }
            run = ge;
        }
    }
    __syncthreads();
    const unsigned int b1 = sres[0], kk1 = sres[1];
    const unsigned int b2 = sres[2], kk2 = sres[3];

    // gather boundary-bin candidates (j = lane*16 + i)
#pragma unroll
    for (int i = 0; i < 16; ++i) {
        int j = lane * 16 + i;
        unsigned long long pk = ((unsigned long long)u[i] << 32) | (unsigned int)(1023 - j);
        if ((unsigned int)bin[i] == b1) {
            unsigned int p = atomicAdd(&scnt[0], 1u);
            if (p < CAP) cand[0][p] = pk;
        }
        if (b2 != b1 && (unsigned int)bin[i] == b2) {
            unsigned int p = atomicAdd(&scnt[1], 1u);
            if (p < CAP) cand[1][p] = pk;
        }
    }
    __syncthreads();
    const unsigned int C1 = scnt[0];
    const unsigned int C2 = (b2 == b1) ? C1 : scnt[1];
    const unsigned long long* L2 = (b2 == b1) ? cand[0] : cand[1];

    // exact rank within boundary bin
    if (C1 <= CAP) {
        for (unsigned int idx = lane; idx < C1; idx += 64) {
            unsigned long long mine = cand[0][idx];
            unsigned int myu = (unsigned int)(mine >> 32);
            unsigned int rank = 0, gtu = 0;
            for (unsigned int c = 0; c < C1; ++c) {
                unsigned long long o = cand[0][c];
                rank += (o > mine) ? 1u : 0u;
                gtu  += ((unsigned int)(o >> 32) > myu) ? 1u : 0u;
            }
            if (rank == kk1 - 1) { sres[4] = myu; sres[5] = gtu; }
        }
    }
    if (C2 <= CAP) {
        for (unsigned int idx = lane; idx < C2; idx += 64) {
            unsigned long long mine = L2[idx];
            unsigned int myu = (unsigned int)(mine >> 32);
            unsigned int rank = 0, gtu = 0;
            for (unsigned int c = 0; c < C2; ++c) {
                unsigned long long o = L2[c];
                rank += (o > mine) ? 1u : 0u;
                gtu  += ((unsigned int)(o >> 32) > myu) ? 1u : 0u;
            }
            if (rank == kk2 - 1) { sres[6] = myu; sres[7] = gtu; }
        }
    }
    __syncthreads();

    unsigned int T1, T2; int r1, r2;
    if (C1 <= CAP) { T1 = sres[4]; r1 = (int)(kk1 - sres[5]); }
    else           { T1 = bsearch_kth(u, CDIM, lane, &r1); }
    if (C2 <= CAP) { T2 = sres[6]; r2 = (int)(kk2 - sres[7]); }
    else           { T2 = bsearch_kth(u, 2 * CDIM, lane, &r2); }

    // tie ranks for (lane, i) ascending-index order
    int p1[16], p2[16];
    int tot1 = 0, tot2 = 0;
#pragma unroll
    for (int i = 0; i < 16; ++i) {
        p1[i] = tot1; p2[i] = tot2;
        tot1 += (u[i] == T1) ? 1 : 0;
        tot2 += (u[i] == T2) ? 1 : 0;
    }
    int s1v = tot1, s2v = tot2;
#pragma unroll
    for (int off = 1; off < 64; off <<= 1) {
        int o1 = __shfl_up(s1v, off, 64);
        int o2 = __shfl_up(s2v, off, 64);
        if (lane >= off) { s1v += o1; s2v += o2; }
    }
    const int ex1 = s1v - tot1;
    const int ex2 = s2v - tot2;

    // mask_new store: 4x float4
#pragma unroll
    for (int c = 0; c < 4; ++c) {
        float v[4];
#pragma unroll
        for (int x = 0; x < 4; ++x) {
            int i = c * 4 + x;
            bool s1 = (u[i] > T1) || ((u[i] == T1) && (ex1 + p1[i] < r1));
            v[x] = mpv[i] + (s1 ? 1.0f : 0.0f);
        }
        float4 v4 = {v[0], v[1], v[2], v[3]};
        *(float4*)(hrow + c * 4) = v4;
    }
    // Abf store: 2x uint4 (8 bf16 each)
    __hip_bfloat16* ab = Abf + row * HDIM + lane * 16;
#pragma unroll
    for (int half = 0; half < 2; ++half) {
        union { unsigned short us[8]; uint4 v; } pk;
#pragma unroll
        for (int x = 0; x < 8; ++x) {
            int i = half * 8 + x;
            bool s2 = (u[i] > T2) || ((u[i] == T2) && (ex2 + p2[i] < r2));
            __hip_bfloat16 bb = __float2bfloat16(s2 ? hv[i] : 0.0f);
            pk.us[x] = *(unsigned short*)&bb;
        }
        *(uint4*)(ab + half * 8) = pk.v;
    }
}

// ---------------------------------------------------------------------------
// K3: decoder GEMM bf16 MFMA, 128x128 tile, BK=32.
// Round-5: m97-class staging — glds16 (async global->LDS, width 16) into
// LINEAR [128][32] bf16 tiles, double-buffered (32 KB total). Replaces the
// reg-staged padded-LDS path (was 115 µs @ 299 TF; ladder says this staging
// switch is the 517->874 TF step). The 8-way ds_read bank aliasing of the
// 64B-row linear tile is the same one m97 carried at 874 TF — accepted.
// MFMA operands and epilogue unchanged => bit-identical output.
// ---------------------------------------------------------------------------
__global__ __launch_bounds__(256, 2) void k3_dec(const __hip_bfloat16* __restrict__ A,
                                                 const __hip_bfloat16* __restrict__ Bt,
                                                 const float* __restrict__ bias_self,
                                                 const float* __restrict__ bias_src,
                                                 const int* __restrict__ dtype,
                                                 float* __restrict__ Out) {
    __shared__ __align__(16) __hip_bfloat16 As[2][128][32];
    __shared__ __align__(16) __hip_bfloat16 Bs[2][128][32];
    const int t = threadIdx.x;
    const int lane = t & 63;
    const int wave = t >> 6;
    const int m0 = blockIdx.x * 128;
    const int n0 = blockIdx.y * 128;
    const int wr = wave >> 1;
    const int wc = wave & 1;
    const int quad = lane >> 4;
    const int rf = lane & 15;
    const int wavebase = t & ~63;

    // staging: p=0,1; idx = p*256+t -> row = idx>>2 (0..127), slot = idx&3 (16B)
    // glds dest byte = idx*16 (linear) = wave-uniform base + lane*16.
    const __hip_bfloat16* aptr[2];
    const __hip_bfloat16* bptr[2];
#pragma unroll
    for (int p = 0; p < 2; ++p) {
        int idx = p * 256 + t;
        int row = idx >> 2;
        int kc8 = (idx & 3) << 3;   // bf16 elems (8 = 16B)
        aptr[p] = A  + (size_t)(m0 + row) * HDIM + kc8;
        bptr[p] = Bt + (size_t)(n0 + row) * HDIM + kc8;
    }

    floatx4 acc[4][4];
    const floatx4 z = {0.0f, 0.0f, 0.0f, 0.0f};
#pragma unroll
    for (int i = 0; i < 4; ++i)
#pragma unroll
        for (int j = 0; j < 4; ++j) acc[i][j] = z;

    // ---- prologue: stage k-tile 0 into buf 0 ----
#pragma unroll
    for (int p = 0; p < 2; ++p) {
        glds16(aptr[p], (char*)&As[0][0][0] + (size_t)(p * 256 + wavebase) * 16);
        glds16(bptr[p], (char*)&Bs[0][0][0] + (size_t)(p * 256 + wavebase) * 16);
    }
    asm volatile("s_waitcnt vmcnt(0)");
    __syncthreads();

#pragma unroll 1
    for (int kt = 0; kt < HDIM / 32; ++kt) {
        const int cur = kt & 1;
        if (kt < HDIM / 32 - 1) {
            const int kn = (kt + 1) * 32;
#pragma unroll
            for (int p = 0; p < 2; ++p) {
                glds16(aptr[p] + kn,
                       (char*)&As[cur ^ 1][0][0] + (size_t)(p * 256 + wavebase) * 16);
                glds16(bptr[p] + kn,
                       (char*)&Bs[cur ^ 1][0][0] + (size_t)(p * 256 + wavebase) * 16);
            }
        }

        shortx8 af[4], bf[4];
#pragma unroll
        for (int i = 0; i < 4; ++i) {
            af[i] = *(const shortx8*)&As[cur][wr * 64 + i * 16 + rf][quad * 8];
            bf[i] = *(const shortx8*)&Bs[cur][wc * 64 + i * 16 + rf][quad * 8];
        }
#pragma unroll
        for (int mi = 0; mi < 4; ++mi)
#pragma unroll
            for (int nj = 0; nj < 4; ++nj)
                acc[mi][nj] = __builtin_amdgcn_mfma_f32_16x16x32_bf16(
                    af[mi], bf[nj], acc[mi][nj], 0, 0, 0);

        if (kt < HDIM / 32 - 1) {
            asm volatile("s_waitcnt vmcnt(0)");   // issued one compute phase ago
            __syncthreads();
        }
    }

    const float* bias = (*dtype == 0) ? bias_self : bias_src;
#pragma unroll
    for (int mi = 0; mi < 4; ++mi) {
#pragma unroll
        for (int nj = 0; nj < 4; ++nj) {
            int gn = n0 + wc * 64 + nj * 16 + rf;
            float bv = bias[gn];
            int gmb = m0 + wr * 64 + mi * 16 + quad * 4;
#pragma unroll
            for (int r2 = 0; r2 < 4; ++r2)
                Out[(size_t)(gmb + r2) * ODIM + gn] = acc[mi][nj][r2] + bv;
        }
    }
}

// ---------------------------------------------------------------------------
extern "C" void kernel_launch(void* const* d_in, const int* in_sizes, int n_in,
                              void* d_out, int out_size, void* d_ws, size_t ws_size,
                              hipStream_t stream) {
    const float* x          = (const float*)d_in[0];
    const float* mask_prev  = (const float*)d_in[1];
    const float* W_enc      = (const float*)d_in[2];
    const float* b_enc      = (const float*)d_in[3];
    const float* W_dec_self = (const float*)d_in[4];
    const float* b_dec_self = (const float*)d_in[5];
    const float* W_dec_src  = (const float*)d_in[6];
    const float* b_dec_src  = (const float*)d_in[7];
    const int*   dtype      = (const int*)d_in[8];

    float* out  = (float*)d_out;
    float* Hbuf = out + OUT_OFF;   // h staged in mask_new output region (in-place per row)

    __hip_bfloat16* Abf = (__hip_bfloat16*)d_ws;                             // 128 MB
    __hip_bfloat16* WdT = (__hip_bfloat16*)((char*)d_ws + (size_t)M_ * HDIM * 2);

    k0_convw<<<dim3((ODIM * HDIM) / 256), 256, 0, stream>>>(W_dec_self, W_dec_src, dtype, WdT);
    k1_enc  <<<dim3(M_ / 128, HDIM / 128), 256, 0, stream>>>(x, W_enc, b_enc, Hbuf);
    k2_topk <<<dim3(M_), 64, 0, stream>>>(mask_prev, Hbuf, Abf);
    k3_dec  <<<dim3(M_ / 128, ODIM / 128), 256, 0, stream>>>(Abf, WdT, b_dec_self, b_dec_src, dtype, out);
}